// Round 1
// baseline (749.858 us; speedup 1.0000x reference)
//
#include <hip/hip_runtime.h>
#include <cstdint>
#include <cstddef>

#define NN 50000
#define NE 800000

// ---------------------------------------------------------------------------
// Edge-index dtype robustness: reference says int64, but JAX default config
// canonicalizes to int32. Detect on-device: for int64 data, every high word
// of the first 1024 entries is 0 (values < 50000). flag=1 -> int32 layout.
// ---------------------------------------------------------------------------
__device__ __forceinline__ int edge_at(const void* e, int is32, long long i) {
    return is32 ? ((const int*)e)[i] : (int)((const long long*)e)[i];
}

__global__ __launch_bounds__(64) void zero_flag_k(int* flag) {
    if (threadIdx.x == 0) *flag = 0;
}

__global__ __launch_bounds__(256) void detect_k(const int* __restrict__ w, int* __restrict__ flag) {
    int i = blockIdx.x * 256 + threadIdx.x;   // 0..1023
    if (i < 1024 && w[2 * i + 1] != 0) atomicOr(flag, 1);
}

// ---------------------------------------------------------------------------
// x = qe * obj (Hadamard), vectorized float4
// ---------------------------------------------------------------------------
__global__ __launch_bounds__(256) void hadamard_k(const float4* __restrict__ a,
                                                  const float4* __restrict__ b,
                                                  float4* __restrict__ o, int n4) {
    int i = blockIdx.x * 256 + threadIdx.x;
    if (i < n4) {
        float4 x = a[i], y = b[i];
        o[i] = make_float4(x.x * y.x, x.y * y.y, x.z * y.z, x.w * y.w);
    }
}

// ---------------------------------------------------------------------------
// Degree / CSR build
// ---------------------------------------------------------------------------
__global__ __launch_bounds__(256) void init_k(int* __restrict__ deg, int* __restrict__ cursor, int n) {
    int i = blockIdx.x * 256 + threadIdx.x;
    if (i < n) { deg[i] = 1; cursor[i] = 0; }   // deg starts at 1 (self-loop)
}

__global__ __launch_bounds__(256) void count_k(const void* __restrict__ edges,
                                               const int* __restrict__ flag,
                                               int* __restrict__ deg, int e) {
    int i = blockIdx.x * 256 + threadIdx.x;
    if (i < e) {
        int is32 = *flag;
        int r = edge_at(edges, is32, i);        // edge_index[0] = destination
        atomicAdd(&deg[r], 1);
    }
}

__global__ __launch_bounds__(256) void dinv_k(const int* __restrict__ deg, float* __restrict__ dinv, int n) {
    int i = blockIdx.x * 256 + threadIdx.x;
    if (i < n) dinv[i] = rsqrtf((float)deg[i]); // deg >= 1 always (self-loop)
}

// Exclusive scan of in-edge counts (deg-1) over 50001 entries, single block.
__global__ __launch_bounds__(1024) void scan_k(const int* __restrict__ deg, int* __restrict__ rp, int n) {
    __shared__ int s[1024];
    int t = threadIdx.x;
    int chunk = (n + 1023) / 1024;
    int lo = t * chunk;
    int hi = lo + chunk; if (hi > n) hi = n;
    int sum = 0;
    for (int i = lo; i < hi; ++i) sum += deg[i] - 1;
    s[t] = sum;
    __syncthreads();
    for (int off = 1; off < 1024; off <<= 1) {
        int val = (t >= off) ? s[t - off] : 0;
        __syncthreads();
        s[t] += val;
        __syncthreads();
    }
    int run = (t == 0) ? 0 : s[t - 1];
    for (int i = lo; i < hi; ++i) { rp[i] = run; run += deg[i] - 1; }
    if (t == 1023) rp[n] = s[1023];
}

__global__ __launch_bounds__(256) void scatter_k(const void* __restrict__ edges,
                                                 const int* __restrict__ flag,
                                                 const float* __restrict__ dinv,
                                                 const int* __restrict__ rp,
                                                 int* __restrict__ cursor,
                                                 int* __restrict__ col_s,
                                                 float* __restrict__ norm_s, int e) {
    int i = blockIdx.x * 256 + threadIdx.x;
    if (i < e) {
        int is32 = *flag;
        int r = edge_at(edges, is32, i);                      // dest
        int c = edge_at(edges, is32, (long long)NE + i);      // source
        int pos = rp[r] + atomicAdd(&cursor[r], 1);
        col_s[pos] = c;
        norm_s[pos] = dinv[r] * dinv[c];
    }
}

// ---------------------------------------------------------------------------
// fp32 tiled GEMM: C[M,Nout] = A[M,K] @ W[K,Nout].  BM=BN=64, BK=16,
// 256 threads, 4x4 micro-tile per thread.
// ---------------------------------------------------------------------------
__global__ __launch_bounds__(256) void gemm_k(const float* __restrict__ A,
                                              const float* __restrict__ W,
                                              float* __restrict__ C,
                                              int M, int K, int Nout) {
    __shared__ float As[16][68];   // +4 pad keeps rows 16B-aligned, ~2-way banks
    __shared__ float Bs[16][64];
    int tid = threadIdx.x;
    int bx = blockIdx.x, by = blockIdx.y;
    int tx = tid & 15, ty = tid >> 4;
    int a_row = tid >> 2;
    int a_k4  = (tid & 3) << 2;
    int b_k   = tid >> 4;
    int b_n4  = (tid & 15) << 2;
    int row_g = by * 64 + a_row;
    float acc[4][4] = {};
    for (int k0 = 0; k0 < K; k0 += 16) {
        float4 av = make_float4(0.f, 0.f, 0.f, 0.f);
        if (row_g < M) av = *(const float4*)&A[(size_t)row_g * K + k0 + a_k4];
        As[a_k4 + 0][a_row] = av.x;
        As[a_k4 + 1][a_row] = av.y;
        As[a_k4 + 2][a_row] = av.z;
        As[a_k4 + 3][a_row] = av.w;
        *(float4*)&Bs[b_k][b_n4] =
            *(const float4*)&W[(size_t)(k0 + b_k) * Nout + bx * 64 + b_n4];
        __syncthreads();
        #pragma unroll
        for (int kk = 0; kk < 16; ++kk) {
            float af[4], bf[4];
            #pragma unroll
            for (int i = 0; i < 4; ++i) af[i] = As[kk][ty * 4 + i];
            #pragma unroll
            for (int i = 0; i < 4; ++i) bf[i] = Bs[kk][tx * 4 + i];
            #pragma unroll
            for (int i = 0; i < 4; ++i)
                #pragma unroll
                for (int j = 0; j < 4; ++j)
                    acc[i][j] = fmaf(af[i], bf[j], acc[i][j]);
        }
        __syncthreads();
    }
    #pragma unroll
    for (int i = 0; i < 4; ++i) {
        int r = by * 64 + ty * 4 + i;
        if (r < M)
            *(float4*)&C[(size_t)r * Nout + bx * 64 + tx * 4] =
                make_float4(acc[i][0], acc[i][1], acc[i][2], acc[i][3]);
    }
}

// ---------------------------------------------------------------------------
// Aggregation: one wave per node. out[v] = dinv[v]^2*H[v] + sum norm*H[col] + b
// D=256: lane holds float4; D=128: lane holds float2.
// ---------------------------------------------------------------------------
template <int D, bool RELU>
__global__ __launch_bounds__(256) void aggregate_k(const float* __restrict__ H,
                                                   const float* __restrict__ bias,
                                                   const float* __restrict__ dinv,
                                                   const int* __restrict__ rp,
                                                   const int* __restrict__ cs,
                                                   const float* __restrict__ ns,
                                                   float* __restrict__ Y, int n) {
    constexpr int VEC = D / 64;
    int v = blockIdx.x * 4 + (threadIdx.x >> 6);
    if (v >= n) return;
    int lane = threadIdx.x & 63;
    float dv = dinv[v];
    float self = dv * dv;
    float acc[VEC];
    {
        const float* hv = H + (size_t)v * D + lane * VEC;
        if constexpr (VEC == 4) {
            float4 t = *(const float4*)hv;
            acc[0] = self * t.x; acc[1] = self * t.y; acc[2] = self * t.z; acc[3] = self * t.w;
        } else {
            float2 t = *(const float2*)hv;
            acc[0] = self * t.x; acc[1] = self * t.y;
        }
    }
    int s = rp[v], e = rp[v + 1];
    for (int j = s; j < e; ++j) {
        int c = cs[j];
        float nm = ns[j];
        const float* hc = H + (size_t)c * D + lane * VEC;
        if constexpr (VEC == 4) {
            float4 t = *(const float4*)hc;
            acc[0] += nm * t.x; acc[1] += nm * t.y; acc[2] += nm * t.z; acc[3] += nm * t.w;
        } else {
            float2 t = *(const float2*)hc;
            acc[0] += nm * t.x; acc[1] += nm * t.y;
        }
    }
    float ov[VEC];
    #pragma unroll
    for (int i = 0; i < VEC; ++i) {
        float o = acc[i] + bias[lane * VEC + i];
        if (RELU) o = fmaxf(o, 0.0f);
        ov[i] = o;
    }
    float* yp = Y + (size_t)v * D + lane * VEC;
    if constexpr (VEC == 4) *(float4*)yp = make_float4(ov[0], ov[1], ov[2], ov[3]);
    else                    *(float2*)yp = make_float2(ov[0], ov[1]);
}

// ---------------------------------------------------------------------------
extern "C" void kernel_launch(void* const* d_in, const int* in_sizes, int n_in,
                              void* d_out, int out_size, void* d_ws, size_t ws_size,
                              hipStream_t stream) {
    const float* qe  = (const float*)d_in[0];
    const float* obj = (const float*)d_in[1];
    const void*  edges = d_in[2];
    const float* W1 = (const float*)d_in[3];
    const float* b1 = (const float*)d_in[4];
    const float* W2 = (const float*)d_in[5];
    const float* b2 = (const float*)d_in[6];
    const float* W3 = (const float*)d_in[7];
    const float* b3 = (const float*)d_in[8];
    float* out = (float*)d_out;

    char* p = (char*)d_ws;
    float* A      = (float*)p; p += (size_t)NN * 256 * sizeof(float);  // 51.2 MB
    float* B      = (float*)p; p += (size_t)NN * 256 * sizeof(float);  // 51.2 MB
    int*   deg    = (int*)p;   p += (size_t)NN * 4;
    float* dinv   = (float*)p; p += (size_t)NN * 4;
    int*   rp     = (int*)p;   p += (size_t)(NN + 1) * 4;
    int*   cursor = (int*)p;   p += (size_t)NN * 4;
    int*   col_s  = (int*)p;   p += (size_t)NE * 4;
    float* norm_s = (float*)p; p += (size_t)NE * 4;
    int*   flag   = (int*)p;   p += 4;

    zero_flag_k<<<1, 64, 0, stream>>>(flag);
    detect_k<<<4, 256, 0, stream>>>((const int*)edges, flag);
    hadamard_k<<<(NN * 64 + 255) / 256, 256, 0, stream>>>(
        (const float4*)qe, (const float4*)obj, (float4*)A, NN * 64);
    init_k<<<(NN + 255) / 256, 256, 0, stream>>>(deg, cursor, NN);
    count_k<<<(NE + 255) / 256, 256, 0, stream>>>(edges, flag, deg, NE);
    dinv_k<<<(NN + 255) / 256, 256, 0, stream>>>(deg, dinv, NN);
    scan_k<<<1, 1024, 0, stream>>>(deg, rp, NN);
    scatter_k<<<(NE + 255) / 256, 256, 0, stream>>>(edges, flag, dinv, rp, cursor,
                                                    col_s, norm_s, NE);

    dim3 g1(256 / 64, (NN + 63) / 64);
    dim3 g3(128 / 64, (NN + 63) / 64);
    int aggGrid = (NN + 3) / 4;

    // Layer 1
    gemm_k<<<g1, 256, 0, stream>>>(A, W1, B, NN, 256, 256);
    aggregate_k<256, true><<<aggGrid, 256, 0, stream>>>(B, b1, dinv, rp, col_s, norm_s, A, NN);
    // Layer 2
    gemm_k<<<g1, 256, 0, stream>>>(A, W2, B, NN, 256, 256);
    aggregate_k<256, true><<<aggGrid, 256, 0, stream>>>(B, b2, dinv, rp, col_s, norm_s, A, NN);
    // Layer 3 (no ReLU), writes d_out directly
    gemm_k<<<g3, 256, 0, stream>>>(A, W3, B, NN, 256, 128);
    aggregate_k<128, false><<<aggGrid, 256, 0, stream>>>(B, b3, dinv, rp, col_s, norm_s, out, NN);
}

// Round 2
// 606.129 us; speedup vs baseline: 1.2371x; 1.2371x over previous
//
#include <hip/hip_runtime.h>
#include <cstdint>
#include <cstddef>

#define NN 50000
#define NE 800000

typedef _Float16 f16x8 __attribute__((ext_vector_type(8)));
typedef _Float16 f16x4 __attribute__((ext_vector_type(4)));
typedef float f32x4 __attribute__((ext_vector_type(4)));

// ---------------------------------------------------------------------------
// Edge-index dtype robustness (int64 vs int32 canonicalization)
// ---------------------------------------------------------------------------
__device__ __forceinline__ int edge_at(const void* e, int is32, long long i) {
    return is32 ? ((const int*)e)[i] : (int)((const long long*)e)[i];
}

__global__ __launch_bounds__(64) void zero_flag_k(int* flag) {
    if (threadIdx.x == 0) *flag = 0;
}

__global__ __launch_bounds__(256) void detect_k(const int* __restrict__ w, int* __restrict__ flag) {
    int i = blockIdx.x * 256 + threadIdx.x;   // 0..1023
    if (i < 1024 && w[2 * i + 1] != 0) atomicOr(flag, 1);
}

// ---------------------------------------------------------------------------
// Hadamard: X0 = qe*obj, written as fp16 hi/lo split pair
// ---------------------------------------------------------------------------
__global__ __launch_bounds__(256) void hadamard_k(const float4* __restrict__ a,
                                                  const float4* __restrict__ b,
                                                  _Float16* __restrict__ Xh,
                                                  _Float16* __restrict__ Xl, int n4) {
    int i = blockIdx.x * 256 + threadIdx.x;
    if (i >= n4) return;
    float4 x = a[i], y = b[i];
    float v[4] = { x.x * y.x, x.y * y.y, x.z * y.z, x.w * y.w };
    f16x4 hh, ll;
    #pragma unroll
    for (int j = 0; j < 4; ++j) {
        _Float16 h = (_Float16)v[j];
        hh[j] = h;
        ll[j] = (_Float16)(v[j] - (float)h);
    }
    *(f16x4*)&Xh[(size_t)i * 4] = hh;
    *(f16x4*)&Xl[(size_t)i * 4] = ll;
}

// ---------------------------------------------------------------------------
// Degree / CSR build
// ---------------------------------------------------------------------------
__global__ __launch_bounds__(256) void init_k(int* __restrict__ deg, int* __restrict__ cursor, int n) {
    int i = blockIdx.x * 256 + threadIdx.x;
    if (i < n) { deg[i] = 1; cursor[i] = 0; }   // self-loop
}

__global__ __launch_bounds__(256) void count_k(const void* __restrict__ edges,
                                               const int* __restrict__ flag,
                                               int* __restrict__ deg, int e) {
    int i = blockIdx.x * 256 + threadIdx.x;
    if (i < e) {
        int is32 = *flag;
        atomicAdd(&deg[edge_at(edges, is32, i)], 1);
    }
}

__global__ __launch_bounds__(256) void dinv_k(const int* __restrict__ deg, float* __restrict__ dinv, int n) {
    int i = blockIdx.x * 256 + threadIdx.x;
    if (i < n) dinv[i] = rsqrtf((float)deg[i]);
}

__global__ __launch_bounds__(1024) void scan_k(const int* __restrict__ deg, int* __restrict__ rp, int n) {
    __shared__ int s[1024];
    int t = threadIdx.x;
    int chunk = (n + 1023) / 1024;
    int lo = t * chunk;
    int hi = lo + chunk; if (hi > n) hi = n;
    int sum = 0;
    for (int i = lo; i < hi; ++i) sum += deg[i] - 1;
    s[t] = sum;
    __syncthreads();
    for (int off = 1; off < 1024; off <<= 1) {
        int val = (t >= off) ? s[t - off] : 0;
        __syncthreads();
        s[t] += val;
        __syncthreads();
    }
    int run = (t == 0) ? 0 : s[t - 1];
    for (int i = lo; i < hi; ++i) { rp[i] = run; run += deg[i] - 1; }
    if (t == 1023) rp[n] = s[1023];
}

__global__ __launch_bounds__(256) void scatter_k(const void* __restrict__ edges,
                                                 const int* __restrict__ flag,
                                                 const float* __restrict__ dinv,
                                                 const int* __restrict__ rp,
                                                 int* __restrict__ cursor,
                                                 int* __restrict__ col_s,
                                                 float* __restrict__ norm_s, int e) {
    int i = blockIdx.x * 256 + threadIdx.x;
    if (i < e) {
        int is32 = *flag;
        int r = edge_at(edges, is32, i);
        int c = edge_at(edges, is32, (long long)NE + i);
        int pos = rp[r] + atomicAdd(&cursor[r], 1);
        col_s[pos] = c;
        norm_s[pos] = dinv[r] * dinv[c];
    }
}

// ---------------------------------------------------------------------------
// W convert + transpose: W[K][N] fp32 -> WhT/WlT [N][K] fp16 split
// ---------------------------------------------------------------------------
__global__ __launch_bounds__(256) void wconv_k(const float* __restrict__ W,
                                               _Float16* __restrict__ WhT,
                                               _Float16* __restrict__ WlT,
                                               int K, int Nout) {
    int n = blockIdx.x;
    int k = threadIdx.x;           // K == 256
    float v = W[(size_t)k * Nout + n];
    _Float16 h = (_Float16)v;
    WhT[(size_t)n * K + k] = h;
    WlT[(size_t)n * K + k] = (_Float16)(v - (float)h);
}

// ---------------------------------------------------------------------------
// fp16x3-split MFMA GEMM: C[M,Nout] = (Ah+Al)[M,K] @ (WhT+WlT)^T[K,Nout]
// Block 128x128, 4 waves (2x2), wave tile 64x64, mfma_f32_16x16x32_f16.
// A/B frag: lane holds 8 contiguous k at k=(lane>>4)*8, row/col=lane&15.
// C frag: col=lane&15, row=(lane>>4)*4+reg.
// ---------------------------------------------------------------------------
__global__ __launch_bounds__(256) void gemm_f16x3_k(const _Float16* __restrict__ Ah,
                                                    const _Float16* __restrict__ Al,
                                                    const _Float16* __restrict__ WhT,
                                                    const _Float16* __restrict__ WlT,
                                                    float* __restrict__ C,
                                                    int M, int K, int Nout) {
    // 80B row pitch (40 fp16): start banks cycle period 8 -> 2-way (free)
    __shared__ alignas(16) _Float16 sAh[128][40];
    __shared__ alignas(16) _Float16 sAl[128][40];
    __shared__ alignas(16) _Float16 sBh[128][40];
    __shared__ alignas(16) _Float16 sBl[128][40];

    int tid = threadIdx.x;
    int row0 = blockIdx.y * 128, col0 = blockIdx.x * 128;
    int wid = tid >> 6, lane = tid & 63;
    int wm = wid >> 1, wn = wid & 1;
    int fr = lane & 15;
    int kb = (lane >> 4) * 8;     // k base within 32

    f32x4 acc[4][4] = {};

    for (int k0 = 0; k0 < K; k0 += 32) {
        __syncthreads();
        // stage: 128 rows x 32 k fp16 per tile = 512 x 16B chunks per tile
        #pragma unroll
        for (int c = 0; c < 2; ++c) {
            int ch = tid + c * 256;
            int r = ch >> 2, pe = (ch & 3) * 8;   // element offset within row
            int ar = row0 + r;
            f16x8 vh = {}, vl = {};
            if (ar < M) {
                vh = *(const f16x8*)&Ah[(size_t)ar * K + k0 + pe];
                vl = *(const f16x8*)&Al[(size_t)ar * K + k0 + pe];
            }
            *(f16x8*)&sAh[r][pe] = vh;
            *(f16x8*)&sAl[r][pe] = vl;
            int br = col0 + r;                    // Nout multiple of 128
            *(f16x8*)&sBh[r][pe] = *(const f16x8*)&WhT[(size_t)br * K + k0 + pe];
            *(f16x8*)&sBl[r][pe] = *(const f16x8*)&WlT[(size_t)br * K + k0 + pe];
        }
        __syncthreads();

        f16x8 ah[4], al[4];
        #pragma unroll
        for (int f = 0; f < 4; ++f) {
            int r = wm * 64 + f * 16 + fr;
            ah[f] = *(const f16x8*)&sAh[r][kb];
            al[f] = *(const f16x8*)&sAl[r][kb];
        }
        #pragma unroll
        for (int g = 0; g < 4; ++g) {
            int cc = wn * 64 + g * 16 + fr;
            f16x8 bh = *(const f16x8*)&sBh[cc][kb];
            f16x8 bl = *(const f16x8*)&sBl[cc][kb];
            #pragma unroll
            for (int f = 0; f < 4; ++f) {
                acc[f][g] = __builtin_amdgcn_mfma_f32_16x16x32_f16(ah[f], bh, acc[f][g], 0, 0, 0);
                acc[f][g] = __builtin_amdgcn_mfma_f32_16x16x32_f16(ah[f], bl, acc[f][g], 0, 0, 0);
                acc[f][g] = __builtin_amdgcn_mfma_f32_16x16x32_f16(al[f], bh, acc[f][g], 0, 0, 0);
            }
        }
    }

    int rsub = (lane >> 4) * 4;
    #pragma unroll
    for (int f = 0; f < 4; ++f) {
        #pragma unroll
        for (int g = 0; g < 4; ++g) {
            int col = col0 + wn * 64 + g * 16 + fr;
            #pragma unroll
            for (int r = 0; r < 4; ++r) {
                int row = row0 + wm * 64 + f * 16 + rsub + r;
                if (row < M) C[(size_t)row * Nout + col] = acc[f][g][r];
            }
        }
    }
}

// ---------------------------------------------------------------------------
// Aggregation, one wave per node, edge loop unrolled x4.
// MODE 0: relu, write fp16 hi/lo split (feeds next GEMM)
// MODE 1: no relu, write fp32 (final output)
// ---------------------------------------------------------------------------
template <int D, int MODE>
__global__ __launch_bounds__(256) void aggregate_k(const float* __restrict__ H,
                                                   const float* __restrict__ bias,
                                                   const float* __restrict__ dinv,
                                                   const int* __restrict__ rp,
                                                   const int* __restrict__ cs,
                                                   const float* __restrict__ ns,
                                                   _Float16* __restrict__ Yh,
                                                   _Float16* __restrict__ Yl,
                                                   float* __restrict__ Yf, int n) {
    constexpr int VEC = D / 64;
    int v = blockIdx.x * 4 + (threadIdx.x >> 6);
    if (v >= n) return;
    int lane = threadIdx.x & 63;
    float dv = dinv[v];
    float self = dv * dv;
    float acc[VEC];
    const float* hv = H + (size_t)v * D + lane * VEC;
    #pragma unroll
    for (int i = 0; i < VEC; ++i) acc[i] = self * hv[i];

    int s = rp[v], e = rp[v + 1];
    int j = s;
    for (; j + 4 <= e; j += 4) {
        int c0 = cs[j], c1 = cs[j + 1], c2 = cs[j + 2], c3 = cs[j + 3];
        float n0 = ns[j], n1 = ns[j + 1], n2 = ns[j + 2], n3 = ns[j + 3];
        const float* p0 = H + (size_t)c0 * D + lane * VEC;
        const float* p1 = H + (size_t)c1 * D + lane * VEC;
        const float* p2 = H + (size_t)c2 * D + lane * VEC;
        const float* p3 = H + (size_t)c3 * D + lane * VEC;
        if constexpr (VEC == 4) {
            float4 t0 = *(const float4*)p0, t1 = *(const float4*)p1;
            float4 t2 = *(const float4*)p2, t3 = *(const float4*)p3;
            acc[0] += n0 * t0.x + n1 * t1.x + n2 * t2.x + n3 * t3.x;
            acc[1] += n0 * t0.y + n1 * t1.y + n2 * t2.y + n3 * t3.y;
            acc[2] += n0 * t0.z + n1 * t1.z + n2 * t2.z + n3 * t3.z;
            acc[3] += n0 * t0.w + n1 * t1.w + n2 * t2.w + n3 * t3.w;
        } else {
            float2 t0 = *(const float2*)p0, t1 = *(const float2*)p1;
            float2 t2 = *(const float2*)p2, t3 = *(const float2*)p3;
            acc[0] += n0 * t0.x + n1 * t1.x + n2 * t2.x + n3 * t3.x;
            acc[1] += n0 * t0.y + n1 * t1.y + n2 * t2.y + n3 * t3.y;
        }
    }
    for (; j < e; ++j) {
        int c = cs[j];
        float nm = ns[j];
        const float* hc = H + (size_t)c * D + lane * VEC;
        if constexpr (VEC == 4) {
            float4 t = *(const float4*)hc;
            acc[0] += nm * t.x; acc[1] += nm * t.y; acc[2] += nm * t.z; acc[3] += nm * t.w;
        } else {
            float2 t = *(const float2*)hc;
            acc[0] += nm * t.x; acc[1] += nm * t.y;
        }
    }

    #pragma unroll
    for (int i = 0; i < VEC; ++i) acc[i] += bias[lane * VEC + i];

    if constexpr (MODE == 0) {
        f16x4 hh, ll;
        #pragma unroll
        for (int i = 0; i < VEC; ++i) {
            float o = fmaxf(acc[i], 0.0f);
            _Float16 h = (_Float16)o;
            hh[i] = h;
            ll[i] = (_Float16)(o - (float)h);
        }
        *(f16x4*)&Yh[(size_t)v * D + lane * VEC] = hh;
        *(f16x4*)&Yl[(size_t)v * D + lane * VEC] = ll;
    } else {
        float* yp = Yf + (size_t)v * D + lane * VEC;
        if constexpr (VEC == 4)
            *(float4*)yp = make_float4(acc[0], acc[1], acc[2], acc[3]);
        else
            *(float2*)yp = make_float2(acc[0], acc[1]);
    }
}

// ---------------------------------------------------------------------------
extern "C" void kernel_launch(void* const* d_in, const int* in_sizes, int n_in,
                              void* d_out, int out_size, void* d_ws, size_t ws_size,
                              hipStream_t stream) {
    const float* qe  = (const float*)d_in[0];
    const float* obj = (const float*)d_in[1];
    const void*  edges = d_in[2];
    const float* W1 = (const float*)d_in[3];
    const float* b1 = (const float*)d_in[4];
    const float* W2 = (const float*)d_in[5];
    const float* b2 = (const float*)d_in[6];
    const float* W3 = (const float*)d_in[7];
    const float* b3 = (const float*)d_in[8];
    float* out = (float*)d_out;

    char* p = (char*)d_ws;
    _Float16* Xh   = (_Float16*)p; p += (size_t)NN * 256 * 2;   // 25.6 MB
    _Float16* Xl   = (_Float16*)p; p += (size_t)NN * 256 * 2;   // 25.6 MB
    float* H       = (float*)p;    p += (size_t)NN * 256 * 4;   // 51.2 MB
    _Float16* Wh   = (_Float16*)p; p += (size_t)256 * 256 * 2;
    _Float16* Wl   = (_Float16*)p; p += (size_t)256 * 256 * 2;
    int*   deg     = (int*)p;   p += (size_t)NN * 4;
    float* dinv    = (float*)p; p += (size_t)NN * 4;
    int*   rp      = (int*)p;   p += (size_t)(NN + 1) * 4;
    int*   cursor  = (int*)p;   p += (size_t)NN * 4;
    int*   col_s   = (int*)p;   p += (size_t)NE * 4;
    float* norm_s  = (float*)p; p += (size_t)NE * 4;
    int*   flag    = (int*)p;   p += 4;

    zero_flag_k<<<1, 64, 0, stream>>>(flag);
    detect_k<<<4, 256, 0, stream>>>((const int*)edges, flag);
    hadamard_k<<<(NN * 64 + 255) / 256, 256, 0, stream>>>(
        (const float4*)qe, (const float4*)obj, Xh, Xl, NN * 64);
    init_k<<<(NN + 255) / 256, 256, 0, stream>>>(deg, cursor, NN);
    count_k<<<(NE + 255) / 256, 256, 0, stream>>>(edges, flag, deg, NE);
    dinv_k<<<(NN + 255) / 256, 256, 0, stream>>>(deg, dinv, NN);
    scan_k<<<1, 1024, 0, stream>>>(deg, rp, NN);
    scatter_k<<<(NE + 255) / 256, 256, 0, stream>>>(edges, flag, dinv, rp, cursor,
                                                    col_s, norm_s, NE);

    int mblk = (NN + 127) / 128;            // 391
    int aggGrid = (NN + 3) / 4;

    // Layer 1
    wconv_k<<<256, 256, 0, stream>>>(W1, Wh, Wl, 256, 256);
    gemm_f16x3_k<<<dim3(2, mblk), 256, 0, stream>>>(Xh, Xl, Wh, Wl, H, NN, 256, 256);
    aggregate_k<256, 0><<<aggGrid, 256, 0, stream>>>(H, b1, dinv, rp, col_s, norm_s,
                                                     Xh, Xl, nullptr, NN);
    // Layer 2
    wconv_k<<<256, 256, 0, stream>>>(W2, Wh, Wl, 256, 256);
    gemm_f16x3_k<<<dim3(2, mblk), 256, 0, stream>>>(Xh, Xl, Wh, Wl, H, NN, 256, 256);
    aggregate_k<256, 0><<<aggGrid, 256, 0, stream>>>(H, b2, dinv, rp, col_s, norm_s,
                                                     Xh, Xl, nullptr, NN);
    // Layer 3
    wconv_k<<<128, 256, 0, stream>>>(W3, Wh, Wl, 256, 128);
    gemm_f16x3_k<<<dim3(1, mblk), 256, 0, stream>>>(Xh, Xl, Wh, Wl, H, NN, 256, 128);
    aggregate_k<128, 1><<<aggGrid, 256, 0, stream>>>(H, b3, dinv, rp, col_s, norm_s,
                                                     nullptr, nullptr, out, NN);
}